// Round 7
// baseline (316.601 us; speedup 1.0000x reference)
//
#include <hip/hip_runtime.h>
#include <stdint.h>

#define T_TOK 8192
#define NEXP  8
#define DIMSZ 1024
#define HIDSZ 2048
#define BK    64

typedef __attribute__((ext_vector_type(4))) float f32x4;
typedef __attribute__((ext_vector_type(8))) short s16x8;

// ---------- helpers ----------

__device__ __forceinline__ uint16_t f2bf(float f) {
  uint32_t u = __builtin_bit_cast(uint32_t, f);
  u += 0x7fffu + ((u >> 16) & 1u);   // RNE
  return (uint16_t)(u >> 16);
}

#if __has_builtin(__builtin_amdgcn_cvt_pk_bf16_f32)
typedef __attribute__((ext_vector_type(2))) __bf16 bf16x2;
__device__ __forceinline__ uint32_t pk2(float a, float b) {
  bf16x2 r = __builtin_amdgcn_cvt_pk_bf16_f32(a, b);   // RNE, matches f2bf
  return __builtin_bit_cast(uint32_t, r);
}
#else
__device__ __forceinline__ uint32_t pk2(float a, float b) {
  return (uint32_t)f2bf(a) | ((uint32_t)f2bf(b) << 16);
}
#endif

// async global->LDS, 16B per lane; HW writes base + lane*16 (wave-uniform base).
__device__ __forceinline__ void gload_lds16(const void* g, const void* lds_base) {
  __builtin_amdgcn_global_load_lds(
      (const __attribute__((address_space(1))) uint32_t*)(uintptr_t)g,
      (__attribute__((address_space(3))) uint32_t*)(uint32_t)(uintptr_t)lds_base,
      16, 0, 0);
}

// ---------- convert x only (+ offsets in block 0) ----------
// x: 8.4M f32 -> bf16. 512 blocks x 256 thr x 8 units (unit = 8 floats).

__global__ void cvt_x(const float* __restrict__ x, uint16_t* __restrict__ xb,
                      const int* __restrict__ counts, int* __restrict__ offs,
                      int* __restrict__ toffs) {
  if (blockIdx.x == 0 && threadIdx.x == 0) {
    int s = 0, ts = 0;
    for (int e = 0; e < NEXP; ++e) {
      offs[e] = s; toffs[e] = ts;
      s += counts[e]; ts += (counts[e] + 127) >> 7;
    }
    offs[NEXP] = s; toffs[NEXP] = ts;
  }
  const float4* src = (const float4*)x;
  uint4* dst = (uint4*)xb;
  const size_t base = (size_t)blockIdx.x * 2048;
#pragma unroll
  for (int half = 0; half < 2; ++half) {
    const size_t u0 = base + (size_t)half * 1024 + threadIdx.x;
    float4 v[8];
#pragma unroll
    for (int j = 0; j < 4; ++j) {
      v[2 * j]     = src[2 * (u0 + j * 256)];
      v[2 * j + 1] = src[2 * (u0 + j * 256) + 1];
    }
#pragma unroll
    for (int j = 0; j < 4; ++j) {
      uint4 o;
      o.x = pk2(v[2 * j].x,     v[2 * j].y);
      o.y = pk2(v[2 * j].z,     v[2 * j].w);
      o.z = pk2(v[2 * j + 1].x, v[2 * j + 1].y);
      o.w = pk2(v[2 * j + 1].z, v[2 * j + 1].w);
      dst[u0 + j * 256] = o;
    }
  }
}

// ---------- grouped GEMM: C[m,n] = sum_k A[m,k] * B_e[n,k] ----------
// A: bf16 [*, K] (xb or h).  B: f32 weights [E, N, K] read DIRECTLY (no cvt
// pass) -- staged f32 into LDS by DMA, converted to bf16 in registers at
// fragment-read time (v_cvt_pk_bf16_f32; VALU overlaps MFMA, m114).
// Tile 128x128, BK=64, 4 waves 2x2, 32 MFMA per barrier pair.
// A LDS: 128 x 64 bf16 = 16 KB, 8-chunk rows, swizzle pos = g ^ (r&7) (R6).
// B LDS: 128 x 64 f32 = 32 KB, 16-chunk rows, swizzle pos = g ^ (r&7)
//   -> fragment reads 2-way bank access (free, m136).
// XCD supertile as R4/R6 (FETCH == compulsory).
template <bool OUT_BF16>
__global__ __launch_bounds__(256, 3)
void gemm_grouped(const uint16_t* __restrict__ A, const float* __restrict__ B,
                  void* __restrict__ C, const int* __restrict__ offs,
                  const int* __restrict__ toffs, int N, int K,
                  int mgs, int ntg, int ngx) {
  __shared__ __align__(16) uint16_t As[128 * BK];  // 16 KB bf16
  __shared__ __align__(16) float    Bs[128 * BK];  // 32 KB f32

  const int xcd  = blockIdx.x & 7;
  const int slot = blockIdx.x >> 3;
  const int mg = xcd / ngx, ng = xcd % ngx;
  const int mtg = mg * mgs + slot % mgs;
  const int nt  = ng * ntg + slot / mgs;
  if (mtg >= toffs[NEXP]) return;
  int e = 0;
#pragma unroll
  for (int i = 1; i < NEXP; ++i) e += (toffs[i] <= mtg) ? 1 : 0;
  const int mt      = mtg - toffs[e];
  const int m_start = offs[e];
  const int m_count = offs[e + 1] - m_start;
  const int m0      = mt * 128;
  int valid_m = m_count - m0;
  if (valid_m > 128) valid_m = 128;
  const int n0 = nt * 128;

  const int tid  = threadIdx.x;
  const int lane = tid & 63;
  const int w    = tid >> 6;
  const int wm = w & 1, wn = w >> 1;

  // ---- A staging (bf16, 4 DMAs/iter): slot s=q*256+tid -> row q*32+(tid>>3),
  //      pos tid&7, global chunk g = pos ^ (row&7) = (tid&7) ^ ((tid>>3)&7).
  const int aRow = tid >> 3;                  // 0..31 (per q: +q*32)
  const int aG   = (tid & 7) ^ (aRow & 7);
  const uint16_t* gA = A + (size_t)m_start * K;
  const uint16_t* aP[4];
#pragma unroll
  for (int q = 0; q < 4; ++q) {
    const int rq = q * 32 + aRow;
    const int ar = m0 + (rq < valid_m ? rq : valid_m - 1);  // ragged clamp
    aP[q] = gA + (size_t)ar * K + aG * 8;
  }

  // ---- B staging (f32, 8 DMAs/iter): slot s=q*256+tid -> row q*16+(tid>>4),
  //      pos tid&15, global f32-chunk g = pos ^ (row&7) = (tid&15)^((tid>>4)&7).
  const int bRow = tid >> 4;                  // 0..15 (per q: +q*16)
  const int bG   = (tid & 15) ^ (bRow & 7);
  const float* gB = B + (size_t)e * N * K;
  const float* bP[8];
#pragma unroll
  for (int q = 0; q < 8; ++q)
    bP[q] = gB + (size_t)(n0 + q * 16 + bRow) * K + bG * 4;

  // ---- fragment addresses
  const int fr = lane & 15;
  const int q4 = lane >> 4;
  // A (bf16): half t wants 16B chunk g = t*4 + q4, at pos g ^ (fr&7).
  const int pA0 = ((q4)     ^ (fr & 7)) * 8;
  const int pA1 = ((4 + q4) ^ (fr & 7)) * 8;
  // B (f32): half t wants f32-chunks g0 = t*8 + 2*q4 and g0+1, at pos g^(fr&7).
  const int pB00 = ((2 * q4)     ^ (fr & 7)) * 4;   // f32 elems
  const int pB01 = ((2 * q4 + 1) ^ (fr & 7)) * 4;
  const int pB10 = ((8 + 2 * q4)     ^ (fr & 7)) * 4;
  const int pB11 = ((8 + 2 * q4 + 1) ^ (fr & 7)) * 4;

  f32x4 acc[4][4];
#pragma unroll
  for (int mi = 0; mi < 4; ++mi)
#pragma unroll
    for (int ni = 0; ni < 4; ++ni) acc[mi][ni] = (f32x4){0.f, 0.f, 0.f, 0.f};

  for (int k0 = 0; k0 < K; k0 += BK) {
    __syncthreads();
#pragma unroll
    for (int q = 0; q < 4; ++q) {
      gload_lds16(aP[q], (const char*)As + q * 4096 + w * 1024);
      aP[q] += BK;
    }
#pragma unroll
    for (int q = 0; q < 8; ++q) {
      gload_lds16(bP[q], (const char*)Bs + q * 4096 + w * 1024);
      bP[q] += BK;
    }
    __syncthreads();

    s16x8 af[4][2], bf[4][2];
#pragma unroll
    for (int mi = 0; mi < 4; ++mi) {
      const int r = (wm * 64 + mi * 16 + fr) * BK;
      af[mi][0] = *(const s16x8*)&As[r + pA0];
      af[mi][1] = *(const s16x8*)&As[r + pA1];
    }
#pragma unroll
    for (int ni = 0; ni < 4; ++ni) {
      const int r = (wn * 64 + ni * 16 + fr) * BK;
      f32x4 c00 = *(const f32x4*)&Bs[r + pB00];
      f32x4 c01 = *(const f32x4*)&Bs[r + pB01];
      f32x4 c10 = *(const f32x4*)&Bs[r + pB10];
      f32x4 c11 = *(const f32x4*)&Bs[r + pB11];
      uint4 u0 = make_uint4(pk2(c00[0], c00[1]), pk2(c00[2], c00[3]),
                            pk2(c01[0], c01[1]), pk2(c01[2], c01[3]));
      uint4 u1 = make_uint4(pk2(c10[0], c10[1]), pk2(c10[2], c10[3]),
                            pk2(c11[0], c11[1]), pk2(c11[2], c11[3]));
      bf[ni][0] = __builtin_bit_cast(s16x8, u0);
      bf[ni][1] = __builtin_bit_cast(s16x8, u1);
    }
#pragma unroll
    for (int t = 0; t < 2; ++t)
#pragma unroll
      for (int mi = 0; mi < 4; ++mi)
#pragma unroll
        for (int ni = 0; ni < 4; ++ni)
          acc[mi][ni] = __builtin_amdgcn_mfma_f32_16x16x32_bf16(af[mi][t], bf[ni][t], acc[mi][ni], 0, 0, 0);
  }

  // Epilogue. C/D 16x16 layout: col = lane&15, row = (lane>>4)*4 + reg.
  const int cq = (lane >> 4) * 4;
  const int cc = lane & 15;
#pragma unroll
  for (int mi = 0; mi < 4; ++mi) {
#pragma unroll
    for (int r = 0; r < 4; ++r) {
      const int rt = wm * 64 + mi * 16 + cq + r;
      if (rt < valid_m) {
        const size_t rowoff = (size_t)(m_start + m0 + rt) * N;
#pragma unroll
        for (int ni = 0; ni < 4; ++ni) {
          const int col = n0 + wn * 64 + ni * 16 + cc;
          const float v = acc[mi][ni][r];
          if (OUT_BF16) {
            ((uint16_t*)C)[rowoff + col] = f2bf(v);
          } else {
            const uint32_t bb = (uint32_t)f2bf(v) << 16;  // ref rounds thru bf16
            ((float*)C)[rowoff + col] = __builtin_bit_cast(float, bb);
          }
        }
      }
    }
  }
}

// ---------- launch ----------

extern "C" void kernel_launch(void* const* d_in, const int* in_sizes, int n_in,
                              void* d_out, int out_size, void* d_ws, size_t ws_size,
                              hipStream_t stream) {
  const float* x  = (const float*)d_in[0];   // [T, DIM] f32
  const float* w1 = (const float*)d_in[1];   // [E, HID, DIM] f32
  const float* w2 = (const float*)d_in[2];   // [E, DIM, HID] f32
  const int* cnt  = (const int*)d_in[3];     // [E]
  float* out = (float*)d_out;                // [T, DIM] f32

  char* ws = (char*)d_ws;
  uint16_t* xb = (uint16_t*)ws;              // 16 MB  [T, DIM] bf16
  uint16_t* h  = (uint16_t*)(ws + 16777216); // 32 MB  [T, HID] bf16
  int* offs    = (int*)(ws + 50331648);      // 9 ints
  int* toffs   = offs + 9;                   // 9 ints

  cvt_x<<<512, 256, 0, stream>>>(x, xb, cnt, offs, toffs);

  // GEMM1: h = xb @ bf16(w1)^T  (N=HID, 16 nt, K=DIM). 4 m-grp x 2 n-grp.
  gemm_grouped<true><<<8 * 18 * 8, 256, 0, stream>>>(
      xb, w1, (void*)h, offs, toffs, HIDSZ, DIMSZ, 18, 8, 2);

  // GEMM2: out = h @ bf16(w2)^T  (N=DIM, 8 nt, K=HID). 8 m-grp x 1 n-grp.
  gemm_grouped<false><<<8 * 9 * 8, 256, 0, stream>>>(
      h, w2, (void*)out, offs, toffs, DIMSZ, HIDSZ, 9, 8, 1);
}